// Round 18
// baseline (810.955 us; speedup 1.0000x reference)
//
#include <hip/hip_runtime.h>
#include <stdint.h>

#define NN 50000
#define NE 1600000
#define FIN 128
#define FOUT 64
#define NR 4
#define ROWS 32
#define BSH 6
#define NB 782            // ceil(NN/64) buckets of 64 dsts
#define CAP 4096          // bucket srt capacity (total Poisson(2048))
#define CB 128            // stream blocks for bin
#define EPB 12500         // NE / CB exactly
#define SEG 52            // per-(block,bucket) segment cap (Poisson(16), 4e-6 overflow)
#define GEMM_BLOCKS 1563  // ceil(NN/ROWS)
#define AGG_BLOCKS 3125   // x4 waves = 12500 waves, one dst per wave
#define GA_BASE CB                        // gemm/agg roles start after bin
#define GA_BLOCKS (GEMM_BLOCKS * 3)       // 4689: %3 -> 0 gemm, 1-2 agg
#define FUSE_BLOCKS (GA_BASE + GA_BLOCKS) // 4817

typedef float f4 __attribute__((ext_vector_type(4)));

__device__ __forceinline__ uint32_t f2bf(float f) {   // RNE to bf16 bits
    uint32_t u = __float_as_uint(f);
    u += 0x7FFFu + ((u >> 16) & 1u);
    return u >> 16;
}

// ---------------- init: inverse perm + zero summaries -------------------------
__global__ __launch_bounds__(256) void init_k(const int* __restrict__ perm,
                                              int* __restrict__ invp,
                                              float* __restrict__ summ)
{
    int i = blockIdx.x * 256 + threadIdx.x;
    int r = blockIdx.y;
    if (i < NN) invp[r * NN + perm[r * NN + i]] = i;
    if (r == 0 && blockIdx.x == 0 && i < NR * FOUT) summ[i] = 0.0f;
}

// ---------------- standalone bin (prologue): fixed segments, no bases ---------
__global__ __launch_bounds__(256) void bin_s(const int* __restrict__ ei,
                                             uint16_t* __restrict__ rsrc,
                                             uint8_t*  __restrict__ rdl,
                                             int* __restrict__ cnts)
{
    __shared__ int cur[NB];
    const int blk = blockIdx.x, t = threadIdx.x;
    for (int j = t; j < NB; j += 256) cur[j] = 0;
    __syncthreads();
    const int base = blk * EPB;
    for (int e = t; e < EPB; e += 256) {
        int ee = base + e;
        int src = ei[ee];
        int dst = ei[NE + ee];
        int bkt = dst >> BSH;
        int idx = atomicAdd(&cur[bkt], 1);
        if (idx < SEG) {
            size_t s = ((size_t)bkt * CB + blk) * SEG + idx;
            rsrc[s] = (uint16_t)src;
            rdl[s]  = (uint8_t)(dst & 63);
        }
    }
    __syncthreads();
    for (int j = t; j < NB; j += 256)
        cnts[j * CB + blk] = min(cur[j], SEG);
}

// ---------------- sort: compact 128 segments -> per-dst 8-padded runs ---------
__global__ __launch_bounds__(256) void sort_k(const uint16_t* __restrict__ rsrc,
                                              const uint8_t*  __restrict__ rdl,
                                              const int* __restrict__ cnts,
                                              uint16_t* __restrict__ srt,
                                              uint32_t* __restrict__ dpack)
{
    __shared__ uint32_t sr[CAP];      // 16 KB
    __shared__ int scnt[CB];
    __shared__ int segoff[CB + 1];
    __shared__ int cnt4[4][64];
    __shared__ int start64[64];
    __shared__ int cur4[4][64];
    const int b = blockIdx.x, t = threadIdx.x, w = t >> 6, lane = t & 63;

    if (t < CB) scnt[t] = cnts[b * CB + t];
    cnt4[w][lane] = 0;
    __syncthreads();
    if (t == 0) {
        int a = 0;
        for (int k = 0; k < CB; ++k) { segoff[k] = a; a += scnt[k]; }
        segoff[CB] = a;
    }
    __syncthreads();

    // compact copy: wave w handles segments w*32..w*32+31, one lane per item
    for (int k = 0; k < 32; ++k) {
        int s = w * 32 + k;
        int c = scnt[s];
        if (lane < c) {
            int d = segoff[s] + lane;
            if (d < CAP) {
                size_t g = ((size_t)b * CB + s) * SEG + lane;
                sr[d] = ((uint32_t)rdl[g] << 16) | (uint32_t)rsrc[g];
            }
        }
    }
    __syncthreads();
    const int n = min(segoff[CB], CAP);

    for (int j = t; j < n; j += 256)
        atomicAdd(&cnt4[w][sr[j] >> 16], 1);
    __syncthreads();

    if (t == 0) {
        int acc = 0;
        #pragma unroll 8
        for (int dl = 0; dl < 64; ++dl) {
            int tot = cnt4[0][dl] + cnt4[1][dl] + cnt4[2][dl] + cnt4[3][dl];
            start64[dl] = acc;
            acc += (tot + 7) & ~7;               // 8-pad each run (uint4 loads)
        }
    }
    __syncthreads();

    if (t < 64) {
        int s = start64[t];
        int c0 = cnt4[0][t], c1 = cnt4[1][t], c2 = cnt4[2][t];
        cur4[0][t] = s;
        cur4[1][t] = s + c0;
        cur4[2][t] = s + c0 + c1;
        cur4[3][t] = s + c0 + c1 + c2;
        int dst = b * 64 + t;
        if (dst < NN) {
            int tot = c0 + c1 + c2 + cnt4[3][t];
            dpack[dst] = ((uint32_t)min(tot, 255) << 24) |
                         (uint32_t)(b * CAP + s);
        }
    }
    __syncthreads();

    for (int j = t; j < n; j += 256) {
        uint32_t r = sr[j];
        int dl = r >> 16;
        int idx = atomicAdd(&cur4[w][dl], 1);
        if (idx < CAP) srt[(size_t)b * CAP + idx] = (uint16_t)(r & 0xFFFF);
    }
}

// ---------------- fused: bin[i+1] (blocks 0..127) | gemm[i] || agg[i-1] -------
__global__ __launch_bounds__(256) void fused_k(
    // gemm (relation i):
    const float* __restrict__ x,  const float* __restrict__ pm,
    const float* __restrict__ nm, const float* __restrict__ Wr,
    const uint32_t* __restrict__ dpack_w, const int* __restrict__ invp_r,
    uint32_t* __restrict__ pk_w,
    // agg (relation i-1):
    const uint32_t* __restrict__ dpack_a, const uint16_t* __restrict__ srt_a,
    const uint32_t* __restrict__ pk_a, const float* __restrict__ br_a,
    float* __restrict__ outp_a, float* __restrict__ outn_a,
    float* __restrict__ summ_a,
    // bin (relation i+1):
    const int* __restrict__ ei_bin, uint16_t* __restrict__ rsrc,
    uint8_t* __restrict__ rdl, int* __restrict__ cnts,
    int do_fwd, int do_agg, int do_bin)
{
    __shared__ float sW[FIN * FOUT];   // 32 KB (gemm W; agg reduce; bin cursors)
    __shared__ float sA[ROWS * FIN];   // 16 KB (gemm A, two passes)
    const int t = threadIdx.x;

    if (blockIdx.x < CB) {
        // ---------------- bin role (relation i+1), first generation ----------
        if (!do_bin) return;
        const int blk = blockIdx.x;
        int* cur = (int*)sW;
        for (int j = t; j < NB; j += 256) cur[j] = 0;
        __syncthreads();
        const int base = blk * EPB;
        for (int e = t; e < EPB; e += 256) {
            int ee = base + e;
            int src = ei_bin[ee];
            int dst = ei_bin[NE + ee];
            int bkt = dst >> BSH;
            int idx = atomicAdd(&cur[bkt], 1);
            if (idx < SEG) {
                size_t s = ((size_t)bkt * CB + blk) * SEG + idx;
                rsrc[s] = (uint16_t)src;
                rdl[s]  = (uint8_t)(dst & 63);
            }
        }
        __syncthreads();
        for (int j = t; j < NB; j += 256)
            cnts[j * CB + blk] = min(cur[j], SEG);
        return;
    }

    const int g    = blockIdx.x - GA_BASE;
    const int role = g % 3;
    const int grp  = g / 3;

    if (role == 0) {
        // ---------------- gemm role (two-pass, nontemporal streams) ----------
        if (!do_fwd) return;
        const int row0 = grp * ROWS;

        for (int i = t * 4; i < FIN * FOUT; i += 1024)
            *(f4*)&sW[i] = *(const f4*)&Wr[i];

        const int tr = (t >> 4) * 2;
        const int tc = (t & 15) * 4;
        float accp[2][4] = {{0.f,0.f,0.f,0.f},{0.f,0.f,0.f,0.f}};
        float accn[2][4] = {{0.f,0.f,0.f,0.f},{0.f,0.f,0.f,0.f}};

#define GEMM_PASS(MASKPTR, ACC)                                                 \
        {                                                                       \
            __syncthreads();                                                    \
            for (int i = t * 4; i < ROWS * FIN; i += 1024) {                    \
                int rr = i >> 7, cc = i & 127;                                  \
                int row = row0 + rr;                                            \
                f4 av = (f4)(0.f);                                              \
                if (row < NN) {                                                 \
                    size_t gg = (size_t)row * FIN + cc;                         \
                    f4 xv = __builtin_nontemporal_load((const f4*)(x + gg));    \
                    f4 mv = __builtin_nontemporal_load((const f4*)(MASKPTR + gg));\
                    av = xv * mv;                                               \
                }                                                               \
                *(f4*)&sA[(rr << 7) + (cc ^ ((rr & 7) << 2))] = av;             \
            }                                                                   \
            __syncthreads();                                                    \
            _Pragma("unroll 4")                                                 \
            for (int k = 0; k < FIN; k += 4) {                                  \
                f4 a0 = *(const f4*)&sA[((tr    ) << 7) + (k ^ (((tr    ) & 7) << 2))]; \
                f4 a1 = *(const f4*)&sA[((tr + 1) << 7) + (k ^ (((tr + 1) & 7) << 2))]; \
                _Pragma("unroll")                                               \
                for (int j = 0; j < 4; ++j) {                                   \
                    f4 wv = *(const f4*)&sW[(k + j) * FOUT + tc];               \
                    _Pragma("unroll")                                           \
                    for (int c = 0; c < 4; ++c) {                               \
                        ACC[0][c] += a0[j] * wv[c];                             \
                        ACC[1][c] += a1[j] * wv[c];                             \
                    }                                                           \
                }                                                               \
            }                                                                   \
        }

        GEMM_PASS(pm, accp)
        GEMM_PASS(nm, accn)
#undef GEMM_PASS

        #pragma unroll
        for (int rr = 0; rr < 2; ++rr) {
            int row = row0 + tr + rr;
            if (row >= NN) continue;
            float dp = rsqrtf((float)(dpack_w[row] >> 24) + 1.0f);
            int ni = invp_r[row];
            float dn = rsqrtf((float)(dpack_w[ni] >> 24) + 1.0f);
            #pragma unroll
            for (int c = 0; c < 4; ++c) {
                ((uint16_t*)&pk_w[(size_t)row * 64 + tc + c])[1] = (uint16_t)f2bf(accp[rr][c] * dp);
                ((uint16_t*)&pk_w[(size_t)ni  * 64 + tc + c])[0] = (uint16_t)f2bf(accn[rr][c] * dn);
            }
        }
        return;
    }

    // ---------------- agg role (relation i-1): one wave per dst --------------
    if (!do_agg) return;
    int ab = grp * 2 + (role - 1);
    if (ab >= AGG_BLOCKS) return;

    const int lane = t & 63;
    const int w0 = ab * 4 + (t >> 6);
    const float bl = br_a[lane];
    float part = 0.f;

    for (int dst = w0; dst < NN; dst += 4 * AGG_BLOCKS) {
        uint32_t pc = dpack_a[dst];
        int deg = (int)(pc >> 24);
        const uint16_t* row = srt_a + (pc & 0xFFFFFFu);
        uint32_t gs = pk_a[(size_t)dst * 64 + lane];          // self-loop (scaled)
        float accp = __uint_as_float(gs & 0xFFFF0000u);
        float accn = __uint_as_float(gs << 16);
        int j = 0;
        for (; j + 8 <= deg; j += 8) {
            uint4 rv = *(const uint4*)(row + j);
            int s0 = rv.x & 0xFFFF, s1 = (int)(rv.x >> 16);
            int s2 = rv.y & 0xFFFF, s3 = (int)(rv.y >> 16);
            int s4 = rv.z & 0xFFFF, s5 = (int)(rv.z >> 16);
            int s6 = rv.w & 0xFFFF, s7 = (int)(rv.w >> 16);
            uint32_t g0 = pk_a[(size_t)s0*64+lane], g1 = pk_a[(size_t)s1*64+lane];
            uint32_t g2 = pk_a[(size_t)s2*64+lane], g3 = pk_a[(size_t)s3*64+lane];
            uint32_t g4 = pk_a[(size_t)s4*64+lane], g5 = pk_a[(size_t)s5*64+lane];
            uint32_t g6 = pk_a[(size_t)s6*64+lane], g7 = pk_a[(size_t)s7*64+lane];
            accp += __uint_as_float(g0 & 0xFFFF0000u) + __uint_as_float(g1 & 0xFFFF0000u)
                  + __uint_as_float(g2 & 0xFFFF0000u) + __uint_as_float(g3 & 0xFFFF0000u)
                  + __uint_as_float(g4 & 0xFFFF0000u) + __uint_as_float(g5 & 0xFFFF0000u)
                  + __uint_as_float(g6 & 0xFFFF0000u) + __uint_as_float(g7 & 0xFFFF0000u);
            accn += __uint_as_float(g0 << 16) + __uint_as_float(g1 << 16)
                  + __uint_as_float(g2 << 16) + __uint_as_float(g3 << 16)
                  + __uint_as_float(g4 << 16) + __uint_as_float(g5 << 16)
                  + __uint_as_float(g6 << 16) + __uint_as_float(g7 << 16);
        }
        for (; j < deg; ++j) {
            uint32_t g = pk_a[(size_t)row[j] * 64 + lane];
            accp += __uint_as_float(g & 0xFFFF0000u);
            accn += __uint_as_float(g << 16);
        }
        float d = rsqrtf((float)deg + 1.0f);
        float op = fmaxf(fmaf(d, accp, bl), 0.f);
        float on = fmaxf(fmaf(d, accn, bl), 0.f);
        outp_a[(size_t)dst * FOUT + lane] = op;
        outn_a[(size_t)dst * FOUT + lane] = on;
        part += op;
    }

    sW[t] = part;                                   // reuse sW as reduce buffer
    __syncthreads();
    if (t < 64) {
        float s = sW[t] + sW[t + 64] + sW[t + 128] + sW[t + 192];
        atomicAdd(&summ_a[t], s * (1.0f / NN));
    }
}

extern "C" void kernel_launch(void* const* d_in, const int* in_sizes, int n_in,
                              void* d_out, int out_size, void* d_ws, size_t ws_size,
                              hipStream_t stream)
{
    const float* x    = (const float*)d_in[0];
    const int*   ei   = (const int*)  d_in[1];
    const float* W    = (const float*)d_in[2];
    const float* b    = (const float*)d_in[3];
    const float* pm   = (const float*)d_in[4];
    const float* nm   = (const float*)d_in[5];
    const int*   perm = (const int*)  d_in[6];
    float* out = (float*)d_out;

    // ws (~55.6 MB): invp | cnts | dpack[2] | pk[2] | srt[2] | rsrc | rdl
    int*      invp   = (int*)d_ws;
    int*      cnts   = invp + (size_t)NR * NN;
    uint32_t* dpack0 = (uint32_t*)(cnts + (size_t)NB * CB);
    uint32_t* dpack1 = dpack0 + NN;
    uint32_t* pk0    = dpack1 + NN;
    uint32_t* pk1    = pk0 + (size_t)NN * 64;
    uint16_t* srt0   = (uint16_t*)(pk1 + (size_t)NN * 64);
    uint16_t* srt1   = srt0 + (size_t)NB * CAP;
    uint16_t* rsrc   = srt1 + (size_t)NB * CAP;
    uint8_t*  rdl    = (uint8_t*)(rsrc + (size_t)NB * CB * SEG);
    uint16_t* srts[2]   = {srt0, srt1};
    uint32_t* dpacks[2] = {dpack0, dpack1};
    uint32_t* pks[2]    = {pk0, pk1};

    const size_t NF = (size_t)NN * FOUT;
    float* outp0 = out;
    float* outn0 = out + (size_t)NR * NF;
    float* summ  = out + 2 * (size_t)NR * NF;

    init_k<<<dim3((NN + 255) / 256, NR), 256, 0, stream>>>(perm, invp, summ);

    // prologue: bin(0) + sort(0)
    bin_s <<<dim3(CB), 256, 0, stream>>>(ei, rsrc, rdl, cnts);
    sort_k<<<dim3(NB), 256, 0, stream>>>(rsrc, rdl, cnts, srt0, dpack0);

    for (int i = 0; i <= NR; ++i) {
        int rf = (i < NR) ? i : 0;
        int ra = (i >= 1) ? (i - 1) : 0;
        int rb = (i + 1 < NR) ? (i + 1) : 0;     // bin relation (clamped)
        int do_fwd = (i < NR), do_agg = (i >= 1), do_bin = (i + 1 < NR);
        fused_k<<<dim3(FUSE_BLOCKS), 256, 0, stream>>>(
            x, pm + (size_t)rf * NN * FIN, nm + (size_t)rf * NN * FIN,
            W + (size_t)rf * FIN * FOUT, dpacks[rf & 1], invp + (size_t)rf * NN,
            pks[rf & 1],
            dpacks[ra & 1], srts[ra & 1], pks[ra & 1],
            b + (size_t)ra * FOUT, outp0 + (size_t)ra * NF,
            outn0 + (size_t)ra * NF, summ + (size_t)ra * FOUT,
            ei + (size_t)rb * 2 * NE, rsrc, rdl, cnts,
            do_fwd, do_agg, do_bin);
        if (do_bin)
            sort_k<<<dim3(NB), 256, 0, stream>>>(rsrc, rdl, cnts,
                                                 srts[(i + 1) & 1], dpacks[(i + 1) & 1]);
    }
}

// Round 19
// 745.756 us; speedup vs baseline: 1.0874x; 1.0874x over previous
//
#include <hip/hip_runtime.h>
#include <stdint.h>

#define NN 50000
#define NE 1600000
#define FIN 128
#define FOUT 64
#define NR 4
#define ROWS 32
#define BSH 6
#define NB 782            // ceil(NN/64) buckets of 64 dsts
#define CAP 4096          // bucket capacity (mean 2048, Poisson, >40 sigma)
#define CB 128            // stream blocks for count/bin
#define EPB 12500         // NE / CB exactly
#define GEMM_BLOCKS 1563  // ceil(NN/ROWS)
#define AGG_BLOCKS 3125   // x4 waves = 12500 waves, one dst per wave
#define GA_BASE (2 * CB)                 // gemm/agg roles start after bin+cnt
#define GA_BLOCKS (GEMM_BLOCKS * 3)      // 4689: %3 -> 0 gemm, 1-2 agg
#define FUSE_BLOCKS (GA_BASE + GA_BLOCKS) // 4945

typedef float f4 __attribute__((ext_vector_type(4)));

__device__ __forceinline__ uint32_t f2bf(float f) {   // RNE to bf16 bits
    uint32_t u = __float_as_uint(f);
    u += 0x7FFFu + ((u >> 16) & 1u);
    return u >> 16;
}

// ---------------- init: inverse perm + zero summaries -------------------------
__global__ __launch_bounds__(256) void init_k(const int* __restrict__ perm,
                                              int* __restrict__ invp,
                                              float* __restrict__ summ)
{
    int i = blockIdx.x * 256 + threadIdx.x;
    int r = blockIdx.y;
    if (i < NN) invp[r * NN + perm[r * NN + i]] = i;
    if (r == 0 && blockIdx.x == 0 && i < NR * FOUT) summ[i] = 0.0f;
}

// ---------------- standalone constr stages (prologue use) ---------------------
__global__ __launch_bounds__(256) void cnt_k(const int* __restrict__ eid,
                                             int* __restrict__ counts)
{
    __shared__ int hist[NB];
    for (int j = threadIdx.x; j < NB; j += 256) hist[j] = 0;
    __syncthreads();
    const int base = blockIdx.x * EPB;
    for (int t = threadIdx.x; t < EPB; t += 256)
        atomicAdd(&hist[eid[base + t] >> BSH], 1);
    __syncthreads();
    for (int j = threadIdx.x; j < NB; j += 256)
        counts[blockIdx.x * NB + j] = hist[j];
}

__global__ __launch_bounds__(128) void scan_k(const int* __restrict__ counts,
                                              int* __restrict__ bases,
                                              int* __restrict__ bcnt)
{
    const int b = blockIdx.x, t = threadIdx.x;
    __shared__ int sc[CB];
    int v = counts[t * NB + b];
    sc[t] = v;
    __syncthreads();
    for (int off = 1; off < CB; off <<= 1) {
        int u = (t >= off) ? sc[t - off] : 0;
        __syncthreads();
        sc[t] += u;
        __syncthreads();
    }
    bases[t * NB + b] = b * CAP + (sc[t] - v);
    if (t == CB - 1) bcnt[b] = sc[t];
}

// ---------------- per-bucket counting sort by dst (serial between launches) ---
__global__ __launch_bounds__(256) void sort_k(const uint32_t* __restrict__ recs,
                                              const int* __restrict__ bcnt,
                                              uint16_t* __restrict__ srt,
                                              uint32_t* __restrict__ dpack)
{
    __shared__ uint32_t sr[CAP];      // 16 KB
    __shared__ int cnt4[4][64];
    __shared__ int start64[64];
    __shared__ int cur4[4][64];
    const int b = blockIdx.x, t = threadIdx.x, w = t >> 6;
    const int n = min(bcnt[b], CAP);

    for (int j = t; j < n; j += 256) sr[j] = recs[(size_t)b * CAP + j];
    cnt4[t >> 6][t & 63] = 0;
    __syncthreads();

    for (int j = t; j < n; j += 256)
        atomicAdd(&cnt4[w][sr[j] >> 16], 1);
    __syncthreads();

    if (t == 0) {
        int acc = 0;
        #pragma unroll 8
        for (int dl = 0; dl < 64; ++dl) {
            int tot = cnt4[0][dl] + cnt4[1][dl] + cnt4[2][dl] + cnt4[3][dl];
            start64[dl] = acc;
            acc += (tot + 7) & ~7;               // 8-pad each run (uint4 loads)
        }
    }
    __syncthreads();

    if (t < 64) {
        int s = start64[t];
        int c0 = cnt4[0][t], c1 = cnt4[1][t], c2 = cnt4[2][t];
        cur4[0][t] = s;
        cur4[1][t] = s + c0;
        cur4[2][t] = s + c0 + c1;
        cur4[3][t] = s + c0 + c1 + c2;
        int dst = b * 64 + t;
        if (dst < NN) {
            int tot = c0 + c1 + c2 + cnt4[3][t];
            dpack[dst] = ((uint32_t)min(tot, 255) << 24) |
                         (uint32_t)(b * CAP + s);
        }
    }
    __syncthreads();

    for (int j = t; j < n; j += 256) {
        uint32_t r = sr[j];
        int dl = r >> 16;
        int idx = atomicAdd(&cur4[w][dl], 1);
        if (idx < CAP) srt[(size_t)b * CAP + idx] = (uint16_t)(r & 0xFFFF);
    }
}

// ---------------- fused: bin[i+1] | cnt[i+2] | gemm[i] || agg[i-1] ------------
// bin/cnt occupy blockIdx 0..255 (FIRST generation) so they co-reside with
// agg/gemm and hide under agg's gather-latency bubbles.
__global__ __launch_bounds__(256) void fused_k(
    // gemm (relation i):
    const float* __restrict__ x,  const float* __restrict__ pm,
    const float* __restrict__ nm, const float* __restrict__ Wr,
    const uint32_t* __restrict__ dpack_w, const int* __restrict__ invp_r,
    uint32_t* __restrict__ pk_w,
    // agg (relation i-1):
    const uint32_t* __restrict__ dpack_a, const uint16_t* __restrict__ srt_a,
    const uint32_t* __restrict__ pk_a, const float* __restrict__ br_a,
    float* __restrict__ outp_a, float* __restrict__ outn_a,
    float* __restrict__ summ_a,
    // bin (relation i+1):
    const int* __restrict__ ei_bin, const int* __restrict__ bases_bin,
    uint32_t* __restrict__ recs,
    // cnt (relation i+2):
    const int* __restrict__ eid_cnt, int* __restrict__ counts,
    int do_fwd, int do_agg, int do_bin, int do_cnt)
{
    __shared__ float sW[FIN * FOUT];   // 32 KB (gemm W; agg reduce; bin/cnt LDS)
    __shared__ float sA[ROWS * FIN];   // 16 KB (gemm A, two passes)
    const int t = threadIdx.x;

    if (blockIdx.x < CB) {
        // ---------------- bin role (relation i+1), first generation ----------
        if (!do_bin) return;
        const int blk = blockIdx.x;
        int* cur = (int*)sW;
        for (int j = t; j < NB; j += 256)
            cur[j] = bases_bin[blk * NB + j];
        __syncthreads();
        const int base = blk * EPB;
        for (int e = t; e < EPB; e += 256) {
            int ee = base + e;
            int src = ei_bin[ee];
            int dst = ei_bin[NE + ee];
            int bkt = dst >> BSH;
            int idx = atomicAdd(&cur[bkt], 1);
            if (idx < (bkt + 1) * CAP)
                recs[idx] = ((uint32_t)(dst & 63) << 16) | (uint32_t)src;
        }
        return;
    }

    if (blockIdx.x < GA_BASE) {
        // ---------------- cnt role (relation i+2), first generation ----------
        if (!do_cnt) return;
        const int blk = blockIdx.x - CB;
        int* hist = (int*)sW;
        for (int j = t; j < NB; j += 256) hist[j] = 0;
        __syncthreads();
        const int base = blk * EPB;
        for (int e = t; e < EPB; e += 256)
            atomicAdd(&hist[eid_cnt[base + e] >> BSH], 1);
        __syncthreads();
        for (int j = t; j < NB; j += 256)
            counts[blk * NB + j] = hist[j];
        return;
    }

    const int g    = blockIdx.x - GA_BASE;
    const int role = g % 3;
    const int grp  = g / 3;

    if (role == 0) {
        // ---------------- gemm role (two-pass, nontemporal streams) ----------
        if (!do_fwd) return;
        const int row0 = grp * ROWS;

        for (int i = t * 4; i < FIN * FOUT; i += 1024)
            *(f4*)&sW[i] = *(const f4*)&Wr[i];

        const int tr = (t >> 4) * 2;
        const int tc = (t & 15) * 4;
        float accp[2][4] = {{0.f,0.f,0.f,0.f},{0.f,0.f,0.f,0.f}};
        float accn[2][4] = {{0.f,0.f,0.f,0.f},{0.f,0.f,0.f,0.f}};

#define GEMM_PASS(MASKPTR, ACC)                                                 \
        {                                                                       \
            __syncthreads();                                                    \
            for (int i = t * 4; i < ROWS * FIN; i += 1024) {                    \
                int rr = i >> 7, cc = i & 127;                                  \
                int row = row0 + rr;                                            \
                f4 av = (f4)(0.f);                                              \
                if (row < NN) {                                                 \
                    size_t gg = (size_t)row * FIN + cc;                         \
                    f4 xv = __builtin_nontemporal_load((const f4*)(x + gg));    \
                    f4 mv = __builtin_nontemporal_load((const f4*)(MASKPTR + gg));\
                    av = xv * mv;                                               \
                }                                                               \
                *(f4*)&sA[(rr << 7) + (cc ^ ((rr & 7) << 2))] = av;             \
            }                                                                   \
            __syncthreads();                                                    \
            _Pragma("unroll 4")                                                 \
            for (int k = 0; k < FIN; k += 4) {                                  \
                f4 a0 = *(const f4*)&sA[((tr    ) << 7) + (k ^ (((tr    ) & 7) << 2))]; \
                f4 a1 = *(const f4*)&sA[((tr + 1) << 7) + (k ^ (((tr + 1) & 7) << 2))]; \
                _Pragma("unroll")                                               \
                for (int j = 0; j < 4; ++j) {                                   \
                    f4 wv = *(const f4*)&sW[(k + j) * FOUT + tc];               \
                    _Pragma("unroll")                                           \
                    for (int c = 0; c < 4; ++c) {                               \
                        ACC[0][c] += a0[j] * wv[c];                             \
                        ACC[1][c] += a1[j] * wv[c];                             \
                    }                                                           \
                }                                                               \
            }                                                                   \
        }

        GEMM_PASS(pm, accp)
        GEMM_PASS(nm, accn)
#undef GEMM_PASS

        #pragma unroll
        for (int rr = 0; rr < 2; ++rr) {
            int row = row0 + tr + rr;
            if (row >= NN) continue;
            float dp = rsqrtf((float)(dpack_w[row] >> 24) + 1.0f);
            int ni = invp_r[row];
            float dn = rsqrtf((float)(dpack_w[ni] >> 24) + 1.0f);
            #pragma unroll
            for (int c = 0; c < 4; ++c) {
                ((uint16_t*)&pk_w[(size_t)row * 64 + tc + c])[1] = (uint16_t)f2bf(accp[rr][c] * dp);
                ((uint16_t*)&pk_w[(size_t)ni  * 64 + tc + c])[0] = (uint16_t)f2bf(accn[rr][c] * dn);
            }
        }
        return;
    }

    // ---------------- agg role (relation i-1): one wave per dst --------------
    if (!do_agg) return;
    int ab = grp * 2 + (role - 1);
    if (ab >= AGG_BLOCKS) return;

    const int lane = t & 63;
    const int w0 = ab * 4 + (t >> 6);
    const float bl = br_a[lane];
    float part = 0.f;

    for (int dst = w0; dst < NN; dst += 4 * AGG_BLOCKS) {
        uint32_t pc = dpack_a[dst];
        int deg = (int)(pc >> 24);
        const uint16_t* row = srt_a + (pc & 0xFFFFFFu);
        uint32_t gs = pk_a[(size_t)dst * 64 + lane];          // self-loop (scaled)
        float accp = __uint_as_float(gs & 0xFFFF0000u);
        float accn = __uint_as_float(gs << 16);
        int j = 0;
        for (; j + 8 <= deg; j += 8) {
            uint4 rv = *(const uint4*)(row + j);
            int s0 = rv.x & 0xFFFF, s1 = (int)(rv.x >> 16);
            int s2 = rv.y & 0xFFFF, s3 = (int)(rv.y >> 16);
            int s4 = rv.z & 0xFFFF, s5 = (int)(rv.z >> 16);
            int s6 = rv.w & 0xFFFF, s7 = (int)(rv.w >> 16);
            uint32_t g0 = pk_a[(size_t)s0*64+lane], g1 = pk_a[(size_t)s1*64+lane];
            uint32_t g2 = pk_a[(size_t)s2*64+lane], g3 = pk_a[(size_t)s3*64+lane];
            uint32_t g4 = pk_a[(size_t)s4*64+lane], g5 = pk_a[(size_t)s5*64+lane];
            uint32_t g6 = pk_a[(size_t)s6*64+lane], g7 = pk_a[(size_t)s7*64+lane];
            accp += __uint_as_float(g0 & 0xFFFF0000u) + __uint_as_float(g1 & 0xFFFF0000u)
                  + __uint_as_float(g2 & 0xFFFF0000u) + __uint_as_float(g3 & 0xFFFF0000u)
                  + __uint_as_float(g4 & 0xFFFF0000u) + __uint_as_float(g5 & 0xFFFF0000u)
                  + __uint_as_float(g6 & 0xFFFF0000u) + __uint_as_float(g7 & 0xFFFF0000u);
            accn += __uint_as_float(g0 << 16) + __uint_as_float(g1 << 16)
                  + __uint_as_float(g2 << 16) + __uint_as_float(g3 << 16)
                  + __uint_as_float(g4 << 16) + __uint_as_float(g5 << 16)
                  + __uint_as_float(g6 << 16) + __uint_as_float(g7 << 16);
        }
        for (; j < deg; ++j) {
            uint32_t g = pk_a[(size_t)row[j] * 64 + lane];
            accp += __uint_as_float(g & 0xFFFF0000u);
            accn += __uint_as_float(g << 16);
        }
        float d = rsqrtf((float)deg + 1.0f);
        float op = fmaxf(fmaf(d, accp, bl), 0.f);
        float on = fmaxf(fmaf(d, accn, bl), 0.f);
        outp_a[(size_t)dst * FOUT + lane] = op;
        outn_a[(size_t)dst * FOUT + lane] = on;
        part += op;
    }

    sW[t] = part;                                   // reuse sW as reduce buffer
    __syncthreads();
    if (t < 64) {
        float s = sW[t] + sW[t + 64] + sW[t + 128] + sW[t + 192];
        atomicAdd(&summ_a[t], s * (1.0f / NN));
    }
}

extern "C" void kernel_launch(void* const* d_in, const int* in_sizes, int n_in,
                              void* d_out, int out_size, void* d_ws, size_t ws_size,
                              hipStream_t stream)
{
    const float* x    = (const float*)d_in[0];
    const int*   ei   = (const int*)  d_in[1];
    const float* W    = (const float*)d_in[2];
    const float* b    = (const float*)d_in[3];
    const float* pm   = (const float*)d_in[4];
    const float* nm   = (const float*)d_in[5];
    const int*   perm = (const int*)  d_in[6];
    float* out = (float*)d_out;

    // ws (~53 MB): invp | counts | bases | bcnt(800) | recs | srt[2] | dpack[2] | pk[2]
    int*      invp   = (int*)d_ws;
    int*      counts = invp + (size_t)NR * NN;
    int*      bases  = counts + (size_t)CB * NB;
    int*      bcnt   = bases + (size_t)CB * NB;
    uint32_t* recs   = (uint32_t*)(bcnt + 800);
    uint16_t* srt0   = (uint16_t*)(recs + (size_t)NB * CAP);
    uint16_t* srt1   = srt0 + (size_t)NB * CAP;
    uint32_t* dpack0 = (uint32_t*)(srt1 + (size_t)NB * CAP);
    uint32_t* dpack1 = dpack0 + NN;
    uint32_t* pk0    = dpack1 + NN;
    uint32_t* pk1    = pk0 + (size_t)NN * 64;
    uint16_t* srts[2]   = {srt0, srt1};
    uint32_t* dpacks[2] = {dpack0, dpack1};
    uint32_t* pks[2]    = {pk0, pk1};

    const size_t NF = (size_t)NN * FOUT;
    float* outp0 = out;
    float* outn0 = out + (size_t)NR * NF;
    float* summ  = out + 2 * (size_t)NR * NF;

    init_k<<<dim3((NN + 255) / 256, NR), 256, 0, stream>>>(perm, invp, summ);

    // prologue: cnt(0); scan(0); {bin(0) || cnt(1)} fused; sort(0); scan(1)
    cnt_k <<<dim3(CB), 256, 0, stream>>>(ei + NE, counts);
    scan_k<<<dim3(NB), 128, 0, stream>>>(counts, bases, bcnt);
    fused_k<<<dim3(FUSE_BLOCKS), 256, 0, stream>>>(
        x, pm, nm, W, dpack0, invp, pk0,                 // gemm args (inactive)
        dpack0, srt0, pk0, b, outp0, outn0, summ,        // agg args (inactive)
        ei, bases, recs,                                 // bin: relation 0
        ei + (size_t)1 * 2 * NE + NE, counts,            // cnt: relation 1
        0, 0, 1, 1);
    sort_k<<<dim3(NB), 256, 0, stream>>>(recs, bcnt, srt0, dpack0);
    scan_k<<<dim3(NB), 128, 0, stream>>>(counts, bases, bcnt);

    for (int i = 0; i <= NR; ++i) {
        int rf = (i < NR) ? i : 0;
        int ra = (i >= 1) ? (i - 1) : 0;
        int rb = (i + 1 < NR) ? (i + 1) : 0;     // bin relation (clamped)
        int rc = (i + 2 < NR) ? (i + 2) : 0;     // cnt relation (clamped)
        int do_fwd = (i < NR), do_agg = (i >= 1);
        int do_bin = (i + 1 < NR), do_cnt = (i + 2 < NR);
        fused_k<<<dim3(FUSE_BLOCKS), 256, 0, stream>>>(
            x, pm + (size_t)rf * NN * FIN, nm + (size_t)rf * NN * FIN,
            W + (size_t)rf * FIN * FOUT, dpacks[rf & 1], invp + (size_t)rf * NN,
            pks[rf & 1],
            dpacks[ra & 1], srts[ra & 1], pks[ra & 1],
            b + (size_t)ra * FOUT, outp0 + (size_t)ra * NF,
            outn0 + (size_t)ra * NF, summ + (size_t)ra * FOUT,
            ei + (size_t)rb * 2 * NE, bases, recs,
            ei + (size_t)rc * 2 * NE + NE, counts,
            do_fwd, do_agg, do_bin, do_cnt);
        if (do_bin)
            sort_k<<<dim3(NB), 256, 0, stream>>>(recs, bcnt,
                                                 srts[(i + 1) & 1], dpacks[(i + 1) & 1]);
        if (do_cnt)
            scan_k<<<dim3(NB), 128, 0, stream>>>(counts, bases, bcnt);
    }
}